// Round 5
// baseline (89048.865 us; speedup 1.0000x reference)
//
#include <hip/hip_runtime.h>

#define BATCH 32
#define SEQ   2048
#define ISZ   512
#define HSZ   512
#define GRID  256
#define TPB   512
#define NB    4      // batches per group (8 groups of 32 blocks)
#define ND    16     // dims per block
#define SPIN_CAP 2000000

typedef unsigned int u32;
typedef unsigned long long u64;

// Exchange protocol (tagged LLC ring, zero-fence): h is exchanged through a
// 2-slot ring in ws (2 x 32 x 512 f32 = 256 KB). Producer stores each h
// value with a 2-bit step tag in the mantissa LSBs (<=3 ulp, irrelevant at
// threshold 2.2e-2) via agent-scope atomic stores -- NO vmcnt, NO beacon:
// every dword is self-validating, so no store ordering is required. Depth-2
// slot reuse is safe by the skew<=1 invariant: a producer reaches step t+2
// only after consuming all h[t+1], which requires every consumer of slot
// t&1 already read it. Ring init 0xFF (tag=3) cannot alias: slot-1 polls
// for tag 3 first occur at t-1=3, after the line was overwritten at t-1=1.
// Consumers poll their own 16 B with agent-scope atomic loads (proven
// semantics, rounds 0-2); the data arrives WITH the successful poll -- one
// LLC round trip, nothing else on the chain. `out` stores are deferred to
// the next iteration's top and issued AFTER the poll loads, so the poll's
// s_waitcnt (in-order vmcnt) never drains the HBM write -- that drain was
// round 2's hidden regression. One __syncthreads per step (was 3).
// Rounds 3-4 lesson: hand-rolled sc0/sc1 flag loads never saw producer
// stores (systematic spin-timeouts) -- only compiler atomics are used here.

__device__ __forceinline__ float u2f(u32 u){ union{u32 u; float f;}c; c.u=u; return c.f; }
__device__ __forceinline__ u32 f2u(float f){ union{float f; u32 u;}c; c.f=f; return c.u; }

__device__ __forceinline__ u64 ld_agent_u64(const u64* p){
    return __hip_atomic_load(p, __ATOMIC_RELAXED, __HIP_MEMORY_SCOPE_AGENT);
}
__device__ __forceinline__ void st_agent_u32(u32* p, u32 v){
    __hip_atomic_store(p, v, __ATOMIC_RELAXED, __HIP_MEMORY_SCOPE_AGENT);
}

#define FMA16(a, W) \
    a = fmaf(W[0].x,o0.x,a); a = fmaf(W[0].y,o0.y,a); a = fmaf(W[0].z,o0.z,a); a = fmaf(W[0].w,o0.w,a); \
    a = fmaf(W[1].x,o1.x,a); a = fmaf(W[1].y,o1.y,a); a = fmaf(W[1].z,o1.z,a); a = fmaf(W[1].w,o1.w,a); \
    a = fmaf(W[2].x,o2.x,a); a = fmaf(W[2].y,o2.y,a); a = fmaf(W[2].z,o2.z,a); a = fmaf(W[2].w,o2.w,a); \
    a = fmaf(W[3].x,o3.x,a); a = fmaf(W[3].y,o3.y,a); a = fmaf(W[3].z,o3.z,a); a = fmaf(W[3].w,o3.w,a);

#define GATE(b, cprev, huout) { \
    float iv = acc[0*4+(b)] + bias0; \
    float fv = acc[1*4+(b)] + bias1; \
    float gv = acc[2*4+(b)] + bias2; \
    float ov = acc[3*4+(b)] + bias3; \
    iv = 1.f/(1.f+__expf(-iv)); \
    fv = 1.f/(1.f+__expf(-fv)); \
    gv = tanhf(gv); \
    ov = 1.f/(1.f+__expf(-ov)); \
    float c = fv*(cprev) + iv*gv; \
    float h = ov*tanhf(c); \
    (cprev) = c; \
    (huout) = (f2u(h) & ~3u) | tg2; }

__global__ __launch_bounds__(TPB)
void lstm_persistent(const float* __restrict__ inp,
                     const float* __restrict__ w_ii, const float* __restrict__ w_hi,
                     const float* __restrict__ b_ii, const float* __restrict__ b_hi,
                     const float* __restrict__ w_if, const float* __restrict__ w_hf,
                     const float* __restrict__ b_if, const float* __restrict__ b_hf,
                     const float* __restrict__ w_io, const float* __restrict__ w_ho,
                     const float* __restrict__ b_io, const float* __restrict__ b_ho,
                     const float* __restrict__ w_ig, const float* __restrict__ w_hg,
                     const float* __restrict__ b_ig, const float* __restrict__ b_hg,
                     float* __restrict__ out, u32* __restrict__ ws)
{
    __shared__ float lh[2][NB * HSZ];       // double-buffered staged h (16 KB)

    const int tid = threadIdx.x;
    const int g   = blockIdx.x;
    u32* ring = ws + 256;                   // byte offset 1024

    const int grp  = g >> 5;                // 8 groups of 32 blocks
    const int rank = g & 31;                // 32 producers/group
    const int B4 = grp * NB;                // this group's 4 batches
    const int d0 = rank * ND;               // this block's 16 dims
    const int dr = tid >> 5;                // dim-within-block 0..15
    const int ks = tid & 31;                // 16-float K-slice
    const int xr = (ks >> 1) & 7;           // hdot XOR swizzle term
    const int bt = tid >> 7;                // staging batch 0..3
    const int cc = tid & 127;               // staging quad 0..127
    const int lb = tid & 31;                // lane within 32-group

    const float* whp[4] = { w_hi, w_hf, w_hg, w_ho };
    const float* wxp[4] = { w_ii, w_if, w_ig, w_io };
    const float* bip[4] = { b_ii, b_if, b_ig, b_io };
    const float* bhp[4] = { b_hi, b_hf, b_hg, b_ho };

    const float bias0 = bip[0][d0 + dr] + bhp[0][d0 + dr];
    const float bias1 = bip[1][d0 + dr] + bhp[1][d0 + dr];
    const float bias2 = bip[2][d0 + dr] + bhp[2][d0 + dr];
    const float bias3 = bip[3][d0 + dr] + bhp[3][d0 + dr];

    // weights in registers: 4 gate-rows (dim d0+dr) x 16-float K-slice of
    // Wx and Wh = 128 floats
    float4 wx[4][4], wh[4][4];
    #pragma unroll
    for (int gi = 0; gi < 4; ++gi) {
        const float* xs = wxp[gi] + (size_t)(d0 + dr) * HSZ + ks * 16;
        const float* hs = whp[gi] + (size_t)(d0 + dr) * HSZ + ks * 16;
        #pragma unroll
        for (int j = 0; j < 4; ++j) {
            wx[gi][j] = *(const float4*)(xs + 4 * j);
            wh[gi][j] = *(const float4*)(hs + 4 * j);
        }
    }

    float xpc[16], xpn[16];                 // x-partials [gate*4 + batch]

    auto xproj = [&](int tt, int blo, int bhi, float* q) {
        #pragma unroll
        for (int b = 0; b < 4; ++b) {
            if (b < blo || b >= bhi) continue;
            const float* src = inp + ((size_t)(B4 + b) * SEQ + tt) * ISZ + ks * 16;
            float4 o0 = *(const float4*)(src);
            float4 o1 = *(const float4*)(src + 4);
            float4 o2 = *(const float4*)(src + 8);
            float4 o3 = *(const float4*)(src + 12);
            #pragma unroll
            for (int gi = 0; gi < 4; ++gi) {
                float a = 0.f;
                FMA16(a, wx[gi]);
                q[gi * 4 + b] = a;
            }
        }
    };

    xproj(0, 0, 4, xpc);                    // prologue

    float c0 = 0.f, c1 = 0.f, c2 = 0.f, c3 = 0.f;
    u32 hu0 = 0, hu1 = 0, hu2 = 0, hu3 = 0;

    for (int t = 0; t < SEQ; ++t) {
        const int slr = (t - 1) & 1;
        if (t > 0) {
            // ---- 1: issue poll loads of this thread's 16 B of h[t-1] ----
            const u64* src = (const u64*)(ring + (size_t)slr * BATCH * HSZ
                                               + (size_t)(B4 + bt) * HSZ + cc * 4);
            u64 v0 = ld_agent_u64(src);
            u64 v1 = ld_agent_u64(src + 1);

            // ---- 2: deferred out-store of h[t-1] (issued AFTER the polls,
            //         so waiting on the polls never drains this HBM write) --
            if (lb < 4) {
                const u32 hu = lb == 0 ? hu0 : lb == 1 ? hu1 : lb == 2 ? hu2 : hu3;
                out[(size_t)(t - 1) * BATCH * HSZ + (size_t)(B4 + lb) * HSZ + (d0 + dr)] = u2f(hu);
            }

            // ---- 3: first half of xproj(t+1) hides the poll latency ----
            if (t + 1 < SEQ) xproj(t + 1, 0, 2, xpn);

            // ---- 4: tag poll -- data in registers on exit ----
            const u32 tg = (u32)((t - 1) & 3);
            int spin = 0;
            while (((((u32)v0 & 3u) == tg) & (((u32)(v0 >> 32) & 3u) == tg) &
                    (((u32)v1 & 3u) == tg) & (((u32)(v1 >> 32) & 3u) == tg)) == 0) {
                __builtin_amdgcn_s_sleep(1);
                v0 = ld_agent_u64(src);
                v1 = ld_agent_u64(src + 1);
                if (++spin > SPIN_CAP) break;
            }

            // ---- 5: stage into LDS, XOR-swizzled at float4 granularity ----
            float4 w;
            w.x = u2f((u32)v0); w.y = u2f((u32)(v0 >> 32));
            w.z = u2f((u32)v1); w.w = u2f((u32)(v1 >> 32));
            const int qs = cc ^ ((cc >> 3) & 7);
            *(float4*)(&lh[slr][bt * 512 + qs * 4]) = w;

            // ---- 6: second half of xproj(t+1) ----
            if (t + 1 < SEQ) xproj(t + 1, 2, 4, xpn);
        } else {
            xproj(1, 0, 4, xpn);
        }
        __syncthreads();                    // the ONLY barrier per step

        // ---- 7: h-dot on top of x partials ----
        float acc[16];
        #pragma unroll
        for (int i = 0; i < 16; ++i) acc[i] = xpc[i];
        if (t > 0) {
            #pragma unroll
            for (int b = 0; b < 4; ++b) {
                const float* hb = &lh[slr][b * 512];
                float4 o0 = *(const float4*)(hb + ((4 * ks + 0) ^ xr) * 4);
                float4 o1 = *(const float4*)(hb + ((4 * ks + 1) ^ xr) * 4);
                float4 o2 = *(const float4*)(hb + ((4 * ks + 2) ^ xr) * 4);
                float4 o3 = *(const float4*)(hb + ((4 * ks + 3) ^ xr) * 4);
                #pragma unroll
                for (int gi = 0; gi < 4; ++gi) {
                    float a = acc[gi * 4 + b];
                    FMA16(a, wh[gi]);
                    acc[gi * 4 + b] = a;
                }
            }
        }
        // ---- 8: butterfly reduce (all lanes get the full sums) ----
        #pragma unroll
        for (int m = 16; m >= 1; m >>= 1) {
            #pragma unroll
            for (int i = 0; i < 16; ++i) acc[i] += __shfl_xor(acc[i], m);
        }

        // ---- 9: gates (replicated per 32-lane group; no LDS, no barrier) --
        const u32 tg2 = (u32)(t & 3);
        GATE(0, c0, hu0)
        GATE(1, c1, hu1)
        GATE(2, c2, hu2)
        GATE(3, c3, hu3)

        // ---- 10: tagged ring store ASAP (agent scope, zero fencing) ----
        if (lb < 4) {
            const u32 hu = lb == 0 ? hu0 : lb == 1 ? hu1 : lb == 2 ? hu2 : hu3;
            st_agent_u32(ring + (size_t)(t & 1) * BATCH * HSZ
                              + (size_t)(B4 + lb) * HSZ + (d0 + dr), hu);
        }

        #pragma unroll
        for (int i = 0; i < 16; ++i) xpc[i] = xpn[i];
    }

    // epilogue: h[SEQ-1], h_last, c_last
    if (lb < 4) {
        const u32 hu  = lb == 0 ? hu0 : lb == 1 ? hu1 : lb == 2 ? hu2 : hu3;
        const float cv = lb == 0 ? c0 : lb == 1 ? c1 : lb == 2 ? c2 : c3;
        out[(size_t)(SEQ - 1) * BATCH * HSZ + (size_t)(B4 + lb) * HSZ + (d0 + dr)] = u2f(hu);
        size_t base = (size_t)SEQ * BATCH * HSZ;
        out[base + (size_t)(B4 + lb) * HSZ + (d0 + dr)] = u2f(hu);                       // h_last
        out[base + (size_t)BATCH * HSZ + (size_t)(B4 + lb) * HSZ + (d0 + dr)] = cv;      // c_last
    }
}

extern "C" void kernel_launch(void* const* d_in, const int* in_sizes, int n_in,
                              void* d_out, int out_size, void* d_ws, size_t ws_size,
                              hipStream_t stream) {
    const float* inp  = (const float*)d_in[0];
    const float* w_ii = (const float*)d_in[1];
    const float* w_hi = (const float*)d_in[2];
    const float* b_ii = (const float*)d_in[3];
    const float* b_hi = (const float*)d_in[4];
    const float* w_if = (const float*)d_in[5];
    const float* w_hf = (const float*)d_in[6];
    const float* b_if = (const float*)d_in[7];
    const float* b_hf = (const float*)d_in[8];
    const float* w_io = (const float*)d_in[9];
    const float* w_ho = (const float*)d_in[10];
    const float* b_io = (const float*)d_in[11];
    const float* b_ho = (const float*)d_in[12];
    const float* w_ig = (const float*)d_in[13];
    const float* w_hg = (const float*)d_in[14];
    const float* b_ig = (const float*)d_in[15];
    const float* b_hg = (const float*)d_in[16];
    float* out = (float*)d_out;
    u32* ws = (u32*)d_ws;

    // 2-slot hot ring at byte offset 1024: init 0xFF (tag=3; cannot alias
    // any first-occupant poll -- see header comment)
    hipMemsetAsync((char*)d_ws + 1024, 0xFF,
                   (size_t)2 * BATCH * HSZ * 4, stream);

    void* args[] = { (void*)&inp,
                     (void*)&w_ii, (void*)&w_hi, (void*)&b_ii, (void*)&b_hi,
                     (void*)&w_if, (void*)&w_hf, (void*)&b_if, (void*)&b_hf,
                     (void*)&w_io, (void*)&w_ho, (void*)&b_io, (void*)&b_ho,
                     (void*)&w_ig, (void*)&w_hg, (void*)&b_ig, (void*)&b_hg,
                     (void*)&out, (void*)&ws };
    hipError_t err = hipLaunchCooperativeKernel((const void*)lstm_persistent,
                                                dim3(GRID), dim3(TPB), args, 0, stream);
    if (err != hipSuccess) {
        lstm_persistent<<<dim3(GRID), dim3(TPB), 0, stream>>>(
            inp, w_ii, w_hi, b_ii, b_hi, w_if, w_hf, b_if, b_hf,
            w_io, w_ho, b_io, b_ho, w_ig, w_hg, b_ig, b_hg, out, ws);
    }
}

// Round 6
// 60455.090 us; speedup vs baseline: 1.4730x; 1.4730x over previous
//
#include <hip/hip_runtime.h>

#define BATCH 32
#define SEQ   2048
#define ISZ   512
#define HSZ   512
#define GRID  256
#define TPB   512
#define NB    4      // batches per group (8 groups x 32 blocks)
#define NPROD 32     // producer blocks per group
#define ND    16     // dims per block
#define SPIN_CAP 2000000

typedef unsigned int u32;
typedef unsigned long long u64;

// Sync protocol: round-0's PROVEN beacon induction, unmodified:
//   producer wave0: agent h-stores -> s_waitcnt vmcnt(0) (ack at coherence
//   point) -> ONE monotone beacon word := t+1. Consumer sees beacon >= t ==>
//   that producer's h[t-1] is visible; data read ONCE afterwards.
// Lessons encoded from rounds 1/2/5 (all regressed or blew up): never
// data-poll shared write-hot lines -- poll only the 32 beacon words
// (2 read-mostly lines/group). What this round cuts vs round 0:
//   - gpre LDS transpose + barrier + serial wave-0 gate math (gates are
//     computed replicated per 32-lane group; thread owns 1 dim x 4 gates)
//   - producer tail: h funneled via 64-word LDS buffer, wave0 issues
//     32 x 8B agent stores (ONE instruction) -> faster vmcnt ack
//   - fan-in 64 -> 32 producers/group (straggler max halved)
//   - per-thread beacon poll (each thread waits only for ITS producer's
//     word) -> S0 barrier deleted; 2 barriers/step instead of 3.
// ws: 256 beacon u32 (zeroed each launch). h exchanged through `out`.

__device__ __forceinline__ float u2f(u32 u){ union{u32 u; float f;}c; c.u=u; return c.f; }
__device__ __forceinline__ u32 f2u(float f){ union{float f; u32 u;}c; c.f=f; return c.u; }

__device__ __forceinline__ u32 ld_agent_u32(const u32* p){
    return __hip_atomic_load(p, __ATOMIC_RELAXED, __HIP_MEMORY_SCOPE_AGENT);
}
__device__ __forceinline__ u64 ld_agent_u64(const u64* p){
    return __hip_atomic_load(p, __ATOMIC_RELAXED, __HIP_MEMORY_SCOPE_AGENT);
}
__device__ __forceinline__ void st_agent_u32(u32* p, u32 v){
    __hip_atomic_store(p, v, __ATOMIC_RELAXED, __HIP_MEMORY_SCOPE_AGENT);
}
__device__ __forceinline__ void st_agent_u64(u64* p, u64 v){
    __hip_atomic_store(p, v, __ATOMIC_RELAXED, __HIP_MEMORY_SCOPE_AGENT);
}

#define FMA16(a, W) \
    a = fmaf(W[0].x,o0.x,a); a = fmaf(W[0].y,o0.y,a); a = fmaf(W[0].z,o0.z,a); a = fmaf(W[0].w,o0.w,a); \
    a = fmaf(W[1].x,o1.x,a); a = fmaf(W[1].y,o1.y,a); a = fmaf(W[1].z,o1.z,a); a = fmaf(W[1].w,o1.w,a); \
    a = fmaf(W[2].x,o2.x,a); a = fmaf(W[2].y,o2.y,a); a = fmaf(W[2].z,o2.z,a); a = fmaf(W[2].w,o2.w,a); \
    a = fmaf(W[3].x,o3.x,a); a = fmaf(W[3].y,o3.y,a); a = fmaf(W[3].z,o3.z,a); a = fmaf(W[3].w,o3.w,a);

#define GATE(b, cprev, huout) { \
    float iv = acc[0*4+(b)] + bias0; \
    float fv = acc[1*4+(b)] + bias1; \
    float gv = acc[2*4+(b)] + bias2; \
    float ov = acc[3*4+(b)] + bias3; \
    iv = 1.f/(1.f+__expf(-iv)); \
    fv = 1.f/(1.f+__expf(-fv)); \
    gv = tanhf(gv); \
    ov = 1.f/(1.f+__expf(-ov)); \
    float c = fv*(cprev) + iv*gv; \
    float h = ov*tanhf(c); \
    (cprev) = c; \
    (huout) = f2u(h); }

__global__ __launch_bounds__(TPB)
void lstm_persistent(const float* __restrict__ inp,
                     const float* __restrict__ w_ii, const float* __restrict__ w_hi,
                     const float* __restrict__ b_ii, const float* __restrict__ b_hi,
                     const float* __restrict__ w_if, const float* __restrict__ w_hf,
                     const float* __restrict__ b_if, const float* __restrict__ b_hf,
                     const float* __restrict__ w_io, const float* __restrict__ w_ho,
                     const float* __restrict__ b_io, const float* __restrict__ b_ho,
                     const float* __restrict__ w_ig, const float* __restrict__ w_hg,
                     const float* __restrict__ b_ig, const float* __restrict__ b_hg,
                     float* __restrict__ out, u32* __restrict__ ws)
{
    __shared__ float lh[2][NB * HSZ];       // double-buffered staged h (16 KB)
    __shared__ u32 hout[64];                // [batch][dim] h funnel for wave 0

    const int tid = threadIdx.x;
    const int g   = blockIdx.x;

    const int grp  = g >> 5;                // 8 groups of 32 blocks
    const int rank = g & 31;
    const int B4 = grp * NB;                // this group's 4 batches
    const int d0 = rank * ND;               // this block's 16 dims
    const int dr = tid >> 5;                // dim-within-block 0..15
    const int ks = tid & 31;                // 16-float K-slice
    const int xr = (ks >> 1) & 7;           // hdot XOR swizzle term
    const int bt = tid >> 7;                // staging batch 0..3
    const int cc = tid & 127;               // staging quad 0..127
    const int lb = tid & 31;                // lane within 32-group

    const float* whp[4] = { w_hi, w_hf, w_hg, w_ho };
    const float* wxp[4] = { w_ii, w_if, w_ig, w_io };
    const float* bip[4] = { b_ii, b_if, b_ig, b_io };
    const float* bhp[4] = { b_hi, b_hf, b_hg, b_ho };

    const float bias0 = bip[0][d0 + dr] + bhp[0][d0 + dr];
    const float bias1 = bip[1][d0 + dr] + bhp[1][d0 + dr];
    const float bias2 = bip[2][d0 + dr] + bhp[2][d0 + dr];
    const float bias3 = bip[3][d0 + dr] + bhp[3][d0 + dr];

    // weights in registers: 4 gate-rows (dim d0+dr) x 16-float K-slice
    float4 wx[4][4], wh[4][4];
    #pragma unroll
    for (int gi = 0; gi < 4; ++gi) {
        const float* xs = wxp[gi] + (size_t)(d0 + dr) * HSZ + ks * 16;
        const float* hs = whp[gi] + (size_t)(d0 + dr) * HSZ + ks * 16;
        #pragma unroll
        for (int j = 0; j < 4; ++j) {
            wx[gi][j] = *(const float4*)(xs + 4 * j);
            wh[gi][j] = *(const float4*)(hs + 4 * j);
        }
    }

    float xpc[16], xpn[16];                 // x-partials [gate*4 + batch]

    auto xproj = [&](int tt, int blo, int bhi, float* q) {
        #pragma unroll
        for (int b = 0; b < 4; ++b) {
            if (b < blo || b >= bhi) continue;
            const float* src = inp + ((size_t)(B4 + b) * SEQ + tt) * ISZ + ks * 16;
            float4 o0 = *(const float4*)(src);
            float4 o1 = *(const float4*)(src + 4);
            float4 o2 = *(const float4*)(src + 8);
            float4 o3 = *(const float4*)(src + 12);
            #pragma unroll
            for (int gi = 0; gi < 4; ++gi) {
                float a = 0.f;
                FMA16(a, wx[gi]);
                q[gi * 4 + b] = a;
            }
        }
    };

    xproj(0, 0, 4, xpc);                    // prologue

    float c0 = 0.f, c1 = 0.f, c2 = 0.f, c3 = 0.f;
    u32 hu0 = 0, hu1 = 0, hu2 = 0, hu3 = 0;

    for (int t = 0; t < SEQ; ++t) {
        const int slr = (t - 1) & 1;
        if (t > 0) {
            // ---- 1: poll THIS thread's producer beacon (2 lines/group) ----
            const u32* bp = ws + grp * NPROD + (cc >> 2);
            u32 bv = ld_agent_u32(bp);
            if (t + 1 < SEQ) xproj(t + 1, 0, 2, xpn);   // hide detect latency
            int spin = 0;
            while (bv < (u32)t) {
                __builtin_amdgcn_s_sleep(1);
                bv = ld_agent_u32(bp);
                if (++spin > SPIN_CAP) break;
            }
            // ---- 2: single read of own 16 B of h[t-1] ----
            const u64* src = (const u64*)(out + (size_t)(t - 1) * BATCH * HSZ
                                              + (size_t)(B4 + bt) * HSZ + cc * 4);
            u64 v0 = ld_agent_u64(src);
            u64 v1 = ld_agent_u64(src + 1);
            if (t + 1 < SEQ) xproj(t + 1, 2, 4, xpn);   // hide read latency
            // ---- 3: stage into LDS, XOR-swizzled ----
            float4 w;
            w.x = u2f((u32)v0); w.y = u2f((u32)(v0 >> 32));
            w.z = u2f((u32)v1); w.w = u2f((u32)(v1 >> 32));
            const int qs = cc ^ ((cc >> 3) & 7);
            *(float4*)(&lh[slr][bt * 512 + qs * 4]) = w;
        } else {
            xproj(1, 0, 4, xpn);
        }
        __syncthreads();                    // (S) staged

        // ---- 4: h-dot on top of x partials ----
        float acc[16];
        #pragma unroll
        for (int i = 0; i < 16; ++i) acc[i] = xpc[i];
        if (t > 0) {
            #pragma unroll
            for (int b = 0; b < 4; ++b) {
                const float* hb = &lh[slr][b * 512];
                float4 o0 = *(const float4*)(hb + ((4 * ks + 0) ^ xr) * 4);
                float4 o1 = *(const float4*)(hb + ((4 * ks + 1) ^ xr) * 4);
                float4 o2 = *(const float4*)(hb + ((4 * ks + 2) ^ xr) * 4);
                float4 o3 = *(const float4*)(hb + ((4 * ks + 3) ^ xr) * 4);
                #pragma unroll
                for (int gi = 0; gi < 4; ++gi) {
                    float a = acc[gi * 4 + b];
                    FMA16(a, wh[gi]);
                    acc[gi * 4 + b] = a;
                }
            }
        }
        // ---- 5: butterfly reduce (all lanes get full sums) ----
        #pragma unroll
        for (int m = 16; m >= 1; m >>= 1) {
            #pragma unroll
            for (int i = 0; i < 16; ++i) acc[i] += __shfl_xor(acc[i], m);
        }

        // ---- 6: gates replicated; funnel h to LDS ----
        GATE(0, c0, hu0)
        GATE(1, c1, hu1)
        GATE(2, c2, hu2)
        GATE(3, c3, hu3)
        if (lb < 4)
            hout[lb * 16 + dr] = lb == 0 ? hu0 : lb == 1 ? hu1 : lb == 2 ? hu2 : hu3;
        __syncthreads();                    // (B) hout ready; lh free

        // ---- 7: wave0: 32x8B agent h-store -> ack -> beacon ----
        if (tid < 32) {
            const u32 lo = hout[tid * 2], hi = hout[tid * 2 + 1];
            const int b2 = tid >> 3, dp = (tid * 2) & 15;
            st_agent_u64((u64*)(out + (size_t)t * BATCH * HSZ
                                    + (size_t)(B4 + b2) * HSZ + d0 + dp),
                         (u64)lo | ((u64)hi << 32));
            if (t + 1 < SEQ) {
                asm volatile("s_waitcnt vmcnt(0)" ::: "memory");   // ack'd
                if (tid == 0) st_agent_u32(ws + grp * NPROD + rank, (u32)(t + 1));
            }
        }

        #pragma unroll
        for (int i = 0; i < 16; ++i) xpc[i] = xpn[i];
    }

    // epilogue: h_last, c_last
    if (lb < 4) {
        const u32 hu  = lb == 0 ? hu0 : lb == 1 ? hu1 : lb == 2 ? hu2 : hu3;
        const float cv = lb == 0 ? c0 : lb == 1 ? c1 : lb == 2 ? c2 : c3;
        size_t base = (size_t)SEQ * BATCH * HSZ;
        out[base + (size_t)(B4 + lb) * HSZ + (d0 + dr)] = u2f(hu);                       // h_last
        out[base + (size_t)BATCH * HSZ + (size_t)(B4 + lb) * HSZ + (d0 + dr)] = cv;      // c_last
    }
}

extern "C" void kernel_launch(void* const* d_in, const int* in_sizes, int n_in,
                              void* d_out, int out_size, void* d_ws, size_t ws_size,
                              hipStream_t stream) {
    const float* inp  = (const float*)d_in[0];
    const float* w_ii = (const float*)d_in[1];
    const float* w_hi = (const float*)d_in[2];
    const float* b_ii = (const float*)d_in[3];
    const float* b_hi = (const float*)d_in[4];
    const float* w_if = (const float*)d_in[5];
    const float* w_hf = (const float*)d_in[6];
    const float* b_if = (const float*)d_in[7];
    const float* b_hf = (const float*)d_in[8];
    const float* w_io = (const float*)d_in[9];
    const float* w_ho = (const float*)d_in[10];
    const float* b_io = (const float*)d_in[11];
    const float* b_ho = (const float*)d_in[12];
    const float* w_ig = (const float*)d_in[13];
    const float* w_hg = (const float*)d_in[14];
    const float* b_ig = (const float*)d_in[15];
    const float* b_hg = (const float*)d_in[16];
    float* out = (float*)d_out;
    u32* ws = (u32*)d_ws;

    hipMemsetAsync(d_ws, 0, 4096, stream);  // zero beacons each launch

    void* args[] = { (void*)&inp,
                     (void*)&w_ii, (void*)&w_hi, (void*)&b_ii, (void*)&b_hi,
                     (void*)&w_if, (void*)&w_hf, (void*)&b_if, (void*)&b_hf,
                     (void*)&w_io, (void*)&w_ho, (void*)&b_io, (void*)&b_ho,
                     (void*)&w_ig, (void*)&w_hg, (void*)&b_ig, (void*)&b_hg,
                     (void*)&out, (void*)&ws };
    hipError_t err = hipLaunchCooperativeKernel((const void*)lstm_persistent,
                                                dim3(GRID), dim3(TPB), args, 0, stream);
    if (err != hipSuccess) {
        lstm_persistent<<<dim3(GRID), dim3(TPB), 0, stream>>>(
            inp, w_ii, w_hi, b_ii, b_hi, w_if, w_hf, b_if, b_hf,
            w_io, w_ho, b_io, b_ho, w_ig, w_hg, b_ig, b_hg, out, ws);
    }
}